// Round 8
// baseline (288.642 us; speedup 1.0000x reference)
//
#include <hip/hip_runtime.h>

typedef __bf16 bf16_8 __attribute__((ext_vector_type(8)));
typedef float  f32x4  __attribute__((ext_vector_type(4)));
typedef float  f32x3  __attribute__((ext_vector_type(3), aligned(4)));

#define INV_SQRT3f 0.57735026918962576f

// R12: R11 (+5% from coalesced staged stores) leaves the per-wave latency-
// serialization model as the only survivor: ~8.3 resident waves/CU * 95us /
// 24.4 waves = each wave lives ~32us for ~2us of work. One-shot waves pay
// queued memory latency ~5x serially, then die. The copy ubench's only
// structural difference is a loop: next loads issue while current stores
// drain. R8's loop spilled (160 prefetch + 80 acc regs); R12 instead gives
// each wave TWO strips with STAGGERED prefetch (only one p1+p2 set fully
// live at once, peak ~200 regs, no spill):
//   A-ph1 -> issue p1B -> A-ph2 -> issue p2B -> A-epilogue (B lands under it)
//   -> B-ph1 -> B-ph2 -> B-epilogue.
// Private 10KB/wave staging (no 2nd barrier; waves desync): w01 leaves LDS
// for the L2/L1-hot global fragment path (1 load -> 3 MFMAs, same shape as
// w10/w11). LDS = 32KB w00 + 4x10KB staging = 72KB -> 2 blocks/CU.
// N=100000 = 3125 pairs exactly (no pair tail).
//
// ws layout (bf16): w00 swz [c=128][q^(c&15)][8] @0 ; w01 LINEAR [64][16][8] @16384
//                   w11 linear [c=128][q=8][8] @24576 ; w10 linear [64][8][8] @32768
// chunk (c,q) element j = W[(q*8+j)*ncols + c]  (B[k][n] layout, k=q*8+j, n=c)
//
// MFMA 16x16x32 bf16 layouts (HW-verified per guide):
//   A: A[m = lane&15][k = (lane>>4)*8 + j], j=0..7
//   B: B[k = (lane>>4)*8 + j][n = lane&15]
//   C/D: D[row = (lane>>4)*4 + r][col = lane&15], r = reg 0..3

__global__ void tp_convert_weights(
    const float* __restrict__ W00, const float* __restrict__ W01,
    const float* __restrict__ W10, const float* __restrict__ W11,
    __bf16* __restrict__ ws)
{
    const int chunk = blockIdx.x * blockDim.x + threadIdx.x;
    bf16_8 v;
    if (chunk < 2048) {                       // W00: 128 cols x K=128, swizzled
        const int c = chunk >> 4, q = chunk & 15;
#pragma unroll
        for (int j = 0; j < 8; ++j) v[j] = (__bf16)W00[(q * 8 + j) * 128 + c];
        *(bf16_8*)(ws + (c * 16 + (q ^ (c & 15))) * 8) = v;
    } else if (chunk < 3072) {                // W01: 64 cols x K=128, LINEAR
        const int idx = chunk - 2048;
        const int c = idx >> 4, q = idx & 15;
#pragma unroll
        for (int j = 0; j < 8; ++j) v[j] = (__bf16)W01[(q * 8 + j) * 64 + c];
        *(bf16_8*)(ws + 16384 + idx * 8) = v;   // idx = c*16+q
    } else if (chunk < 4096) {                // W11: 128 cols x K=64, linear
        const int idx = chunk - 3072;
        const int c = idx >> 3, q = idx & 7;
#pragma unroll
        for (int j = 0; j < 8; ++j) v[j] = (__bf16)W11[(q * 8 + j) * 128 + c];
        *(bf16_8*)(ws + 24576 + idx * 8) = v;   // idx = c*8+q
    } else if (chunk < 4608) {                // W10: 64 cols x K=64, linear
        const int idx = chunk - 4096;
        const int c = idx >> 3, q = idx & 7;
#pragma unroll
        for (int j = 0; j < 8; ++j) v[j] = (__bf16)W10[(q * 8 + j) * 64 + c];
        *(bf16_8*)(ws + 32768 + idx * 8) = v;
    }
}

// ---- macros: all array indices compile-time constant (no scratch) ----
#define LOAD_S1(P1, D2, S) do {                                               \
    int _row = (S) * 16 + mh;  if (_row >= N) _row = N - 1;                   \
    const float* _r1 = din1 + _row * 320 + 8 * kq;                            \
    _Pragma("unroll")                                                         \
    for (int _t = 0; _t < 4; ++_t) {                                          \
        P1[2 * _t]     = *(const f32x4*)(_r1 + 32 * _t);                      \
        P1[2 * _t + 1] = *(const f32x4*)(_r1 + 32 * _t + 4);                  \
    }                                                                         \
    D2 = *(const f32x4*)(din2 + _row * 4);                                    \
} while (0)

#define LOAD_S2(P2, S) do {                                                   \
    int _row = (S) * 16 + mh;  if (_row >= N) _row = N - 1;                   \
    const float* _r2 = din1 + _row * 320 + 128 + 24 * kq;                     \
    _Pragma("unroll")                                                         \
    for (int _h = 0; _h < 2; ++_h)                                            \
        _Pragma("unroll")                                                     \
        for (int _q = 0; _q < 6; ++_q)                                        \
            P2[6 * _h + _q] = *(const f32x4*)(_r2 + 96 * _h + 4 * _q);        \
} while (0)

#define PH1(P1, D2) do {                                                      \
    _Pragma("unroll")                                                         \
    for (int _i = 0; _i < 8; ++_i) accA[_i] = (f32x4)0.0f;                    \
    _Pragma("unroll")                                                         \
    for (int _k = 0; _k < 3; ++_k)                                            \
        _Pragma("unroll")                                                     \
        for (int _i = 0; _i < 4; ++_i) accV[_k][_i] = (f32x4)0.0f;            \
    _Pragma("unroll")                                                         \
    for (int _s = 0; _s < 4; ++_s) {                                          \
        const f32x4 _x0 = P1[2 * _s];                                         \
        const f32x4 _x1 = P1[2 * _s + 1];                                     \
        float _xx[8] = {_x0.x, _x0.y, _x0.z, _x0.w, _x1.x, _x1.y, _x1.z, _x1.w}; \
        bf16_8 _as2, _av0, _av1, _av2;                                        \
        _Pragma("unroll")                                                     \
        for (int _j = 0; _j < 8; ++_j) {                                      \
            _as2[_j] = (__bf16)(D2.x * _xx[_j]);                              \
            _av0[_j] = (__bf16)(D2.y * _xx[_j]);                              \
            _av1[_j] = (__bf16)(D2.z * _xx[_j]);                              \
            _av2[_j] = (__bf16)(D2.w * _xx[_j]);                              \
        }                                                                     \
        const int _q = 4 * _s + kq;                                           \
        _Pragma("unroll")                                                     \
        for (int _nt = 0; _nt < 8; ++_nt) {                                   \
            const int _c = _nt * 16 + mh;                                     \
            bf16_8 _b = *(const bf16_8*)(sw00 + (_c * 16 + (_q ^ mh)) * 8);   \
            accA[_nt] = __builtin_amdgcn_mfma_f32_16x16x32_bf16(_as2, _b, accA[_nt], 0, 0, 0); \
        }                                                                     \
        _Pragma("unroll")                                                     \
        for (int _nt = 0; _nt < 4; ++_nt) {                                   \
            const int _c = _nt * 16 + mh;                                     \
            bf16_8 _b = *(const bf16_8*)(w01g + (_c * 16 + _q) * 8);          \
            accV[0][_nt] = __builtin_amdgcn_mfma_f32_16x16x32_bf16(_av0, _b, accV[0][_nt], 0, 0, 0); \
            accV[1][_nt] = __builtin_amdgcn_mfma_f32_16x16x32_bf16(_av1, _b, accV[1][_nt], 0, 0, 0); \
            accV[2][_nt] = __builtin_amdgcn_mfma_f32_16x16x32_bf16(_av2, _b, accV[2][_nt], 0, 0, 0); \
        }                                                                     \
    }                                                                         \
} while (0)

#define PH2(P2, D2) do {                                                      \
    _Pragma("unroll")                                                         \
    for (int _s = 0; _s < 2; ++_s) {                                          \
        float _b24[24];                                                       \
        _Pragma("unroll")                                                     \
        for (int _qq = 0; _qq < 6; ++_qq) {                                   \
            const f32x4 _t4 = P2[6 * _s + _qq];                               \
            _b24[4 * _qq]     = _t4.x; _b24[4 * _qq + 1] = _t4.y;             \
            _b24[4 * _qq + 2] = _t4.z; _b24[4 * _qq + 3] = _t4.w;             \
        }                                                                     \
        bf16_8 _at, _ac0, _ac1, _ac2;                                         \
        _Pragma("unroll")                                                     \
        for (int _j = 0; _j < 8; ++_j) {                                      \
            const float _e0 = _b24[3 * _j], _e1 = _b24[3 * _j + 1], _e2 = _b24[3 * _j + 2]; \
            _at[_j]  = (__bf16)(INV_SQRT3f * (_e0 * D2.y + _e1 * D2.z + _e2 * D2.w)); \
            _ac0[_j] = (__bf16)(D2.x * _e0);                                  \
            _ac1[_j] = (__bf16)(D2.x * _e1);                                  \
            _ac2[_j] = (__bf16)(D2.x * _e2);                                  \
        }                                                                     \
        const int _q = 4 * _s + kq;                                           \
        _Pragma("unroll")                                                     \
        for (int _nt = 0; _nt < 8; ++_nt) {                                   \
            const int _c = _nt * 16 + mh;                                     \
            bf16_8 _b = *(const bf16_8*)(w11g + (_c * 8 + _q) * 8);           \
            accA[_nt] = __builtin_amdgcn_mfma_f32_16x16x32_bf16(_at, _b, accA[_nt], 0, 0, 0); \
        }                                                                     \
        _Pragma("unroll")                                                     \
        for (int _nt = 0; _nt < 4; ++_nt) {                                   \
            const int _c = _nt * 16 + mh;                                     \
            bf16_8 _b = *(const bf16_8*)(w10g + (_c * 8 + _q) * 8);           \
            accV[0][_nt] = __builtin_amdgcn_mfma_f32_16x16x32_bf16(_ac0, _b, accV[0][_nt], 0, 0, 0); \
            accV[1][_nt] = __builtin_amdgcn_mfma_f32_16x16x32_bf16(_ac1, _b, accV[1][_nt], 0, 0, 0); \
            accV[2][_nt] = __builtin_amdgcn_mfma_f32_16x16x32_bf16(_ac2, _b, accV[2][_nt], 0, 0, 0); \
        }                                                                     \
    }                                                                         \
} while (0)

#define EPI(S) do {                                                           \
    const int _r0 = (S) * 16;                                                 \
    if (_r0 + 16 <= N) {                                                      \
        _Pragma("unroll")                                                     \
        for (int _p = 0; _p < 2; ++_p) {                                      \
            asm volatile("s_waitcnt lgkmcnt(0)" ::: "memory");                \
            if ((kq >> 1) == _p) {                                            \
                const int _rl = 4 * (kq & 1);                                 \
                _Pragma("unroll")                                             \
                for (int _nt = 0; _nt < 8; ++_nt) {                           \
                    const float _bi = bias[_nt * 16 + mh];                    \
                    _Pragma("unroll")                                         \
                    for (int _r = 0; _r < 4; ++_r) {                          \
                        const int _rw = _rl + _r;                             \
                        const int _ch = (_nt * 4 + (mh >> 2)) ^ _rw;          \
                        stgw[_rw * 320 + _ch * 4 + (mh & 3)] = accA[_nt][_r] + _bi; \
                    }                                                         \
                }                                                             \
                _Pragma("unroll")                                             \
                for (int _nt = 0; _nt < 4; ++_nt) {                           \
                    _Pragma("unroll")                                         \
                    for (int _r = 0; _r < 4; ++_r) {                          \
                        const int _rw = _rl + _r;                             \
                        _Pragma("unroll")                                     \
                        for (int _k = 0; _k < 3; ++_k) {                      \
                            const int _f = 128 + 3 * (_nt * 16 + mh) + _k;    \
                            const int _ch = (_f >> 2) ^ _rw;                  \
                            stgw[_rw * 320 + _ch * 4 + (_f & 3)] = accV[_k][_nt][_r]; \
                        }                                                     \
                    }                                                         \
                }                                                             \
            }                                                                 \
            asm volatile("s_waitcnt lgkmcnt(0)" ::: "memory");                \
            __builtin_amdgcn_sched_barrier(0);                                \
            float* _gbase = out + (_r0 + _p * 8) * 320;                       \
            _Pragma("unroll")                                                 \
            for (int _i = 0; _i < 10; ++_i) {                                 \
                const int _v  = _i * 64 + lane;                               \
                const int _rw = _v / 80;                                      \
                const int _ch = (_v % 80) ^ _rw;                              \
                f32x4 _d = *(const f32x4*)(stgw + _rw * 320 + _ch * 4);       \
                __builtin_nontemporal_store(_d, (f32x4*)(_gbase + _v * 4));   \
            }                                                                 \
        }                                                                     \
    } else {                                                                  \
        const int _rowg0 = _r0 + 4 * kq;                                      \
        _Pragma("unroll")                                                     \
        for (int _nt = 0; _nt < 8; ++_nt) {                                   \
            const float _bi = bias[_nt * 16 + mh];                            \
            _Pragma("unroll")                                                 \
            for (int _r = 0; _r < 4; ++_r) {                                  \
                const int _rowg = _rowg0 + _r;                                \
                if (_rowg < N)                                                \
                    __builtin_nontemporal_store(accA[_nt][_r] + _bi,          \
                                                out + _rowg * 320 + _nt * 16 + mh); \
            }                                                                 \
        }                                                                     \
        _Pragma("unroll")                                                     \
        for (int _r = 0; _r < 4; ++_r) {                                      \
            const int _rowg = _rowg0 + _r;                                    \
            if (_rowg < N) {                                                  \
                _Pragma("unroll")                                             \
                for (int _nt = 0; _nt < 4; ++_nt) {                           \
                    const int _w = _nt * 16 + mh;                             \
                    f32x3 _o;                                                 \
                    _o.x = accV[0][_nt][_r];                                  \
                    _o.y = accV[1][_nt][_r];                                  \
                    _o.z = accV[2][_nt][_r];                                  \
                    __builtin_nontemporal_store(_o,                           \
                        (f32x3*)(out + _rowg * 320 + 128 + 3 * _w));          \
                }                                                             \
            }                                                                 \
        }                                                                     \
    }                                                                         \
} while (0)

__global__ __launch_bounds__(256, 2) void tp_main_kernel(
    const float* __restrict__ din1, const float* __restrict__ din2,
    const __bf16* __restrict__ wsw, const float* __restrict__ bias,
    float* __restrict__ out, int N, int npairs)
{
    // 72 KB: 32 KB swizzled w00 + 4 x 10 KB per-wave output staging
    __shared__ __attribute__((aligned(16))) __bf16 smem[36864];
    const __bf16* sw00 = smem;                               // 16384 elems
    float* stgbase = (float*)(smem + 16384);                 // 10240 f32

    const int tid  = threadIdx.x;
    const int wid  = (blockIdx.x << 2) + (tid >> 6);         // pair id
    const int lane = tid & 63;
    const int mh   = lane & 15;
    const int kq   = lane >> 4;
    float* stgw = stgbase + (tid >> 6) * 2560;               // private 10 KB

    const __bf16* __restrict__ w01g = wsw + 16384;
    const __bf16* __restrict__ w11g = wsw + 24576;
    const __bf16* __restrict__ w10g = wsw + 32768;

    // clamped pair for tail waves (prefetch harmlessly, skip compute)
    const int spair = wid < npairs ? wid : npairs - 1;
    const int sA = 2 * spair, sB = 2 * spair + 1;

    // ---- 1) LDS-fill loads (w00 only, 32 KB; barrier-critical) ----
    f32x4 fill[8];
    {
        const f32x4* s = (const f32x4*)wsw;
#pragma unroll
        for (int i = 0; i < 8; ++i) fill[i] = s[tid + 256 * i];
    }

    // ---- 2) strip-A register prefetch burst (hides under fill+barrier) ----
    f32x4 p1A[8], p2A[12], d2A;
    f32x4 p1B[8], p2B[12], d2B;
    LOAD_S1(p1A, d2A, sA);
    LOAD_S2(p2A, sA);

    // ---- 3) LDS writes (wait only on fill loads) + single barrier ----
    {
        f32x4* d = (f32x4*)smem;
#pragma unroll
        for (int i = 0; i < 8; ++i) d[tid + 256 * i] = fill[i];
    }
    __syncthreads();

    if (wid < npairs) {
        f32x4 accA[8];      // out0: 128 cols
        f32x4 accV[3][4];   // outv: 64 w-cols x 3 vector comps

        // ---- strip A compute, with staggered strip-B prefetch ----
        PH1(p1A, d2A);
        LOAD_S1(p1B, d2B, sB);      // p1A dead; B burst flies under A-ph2+epi
        PH2(p2A, d2A);
        LOAD_S2(p2B, sB);           // p2A dead after PH2
        EPI(sA);                    // B loads land under staging+drain

        // ---- strip B ----
        PH1(p1B, d2B);
        PH2(p2B, d2B);
        EPI(sB);
    }
}

extern "C" void kernel_launch(void* const* d_in, const int* in_sizes, int n_in,
                              void* d_out, int out_size, void* d_ws, size_t ws_size,
                              hipStream_t stream)
{
    const float* din1 = (const float*)d_in[0];
    const float* din2 = (const float*)d_in[1];
    const float* W00  = (const float*)d_in[2];
    const float* W01  = (const float*)d_in[3];
    const float* W10  = (const float*)d_in[4];
    const float* W11  = (const float*)d_in[5];
    const float* bias = (const float*)d_in[6];
    float* outp = (float*)d_out;
    __bf16* ws = (__bf16*)d_ws;

    const int N = in_sizes[0] / 320;
    const int npairs  = (N + 31) / 32;          // 32 rows (2 strips) per wave
    const int nblocks = (npairs + 3) / 4;       // 4 waves per 256-thread block

    // 4608 weight chunks, one bf16_8 per thread
    hipLaunchKernelGGL(tp_convert_weights, dim3(18), dim3(256), 0, stream,
                       W00, W01, W10, W11, ws);
    hipLaunchKernelGGL(tp_main_kernel, dim3(nblocks), dim3(256), 0, stream,
                       din1, din2, ws, bias, outp, N, npairs);
}